// Round 4
// baseline (437.592 us; speedup 1.0000x reference)
//
#include <hip/hip_runtime.h>
#include <stdint.h>

typedef __bf16 bf16x8 __attribute__((ext_vector_type(8)));
typedef short s16x8 __attribute__((ext_vector_type(8)));
typedef float f32x4 __attribute__((ext_vector_type(4)));

__device__ __forceinline__ short f2bf(float f) {
  union { __bf16 h; short s; } u;
  u.h = (__bf16)f;   // compiler emits native cvt (RNE) — m240: don't hand-write
  return u.s;
}

// async global -> LDS direct copy, 16B per lane
__device__ __forceinline__ void async_copy16(short* lds, const short* g) {
  __builtin_amdgcn_global_load_lds((const __attribute__((address_space(1))) void*)g,
                                   (__attribute__((address_space(3))) void*)lds,
                                   16, 0, 0);
}

// ---------------- fp32 -> bf16 cast (4 elems/thread) ----------------
__global__ __launch_bounds__(256) void cast_bf16_kernel(const float* __restrict__ in,
                                                        short* __restrict__ out) {
  int i = blockIdx.x * 256 + threadIdx.x;
  float4 v = reinterpret_cast<const float4*>(in)[i];
  short4 o;
  o.x = f2bf(v.x); o.y = f2bf(v.y); o.z = f2bf(v.z); o.w = f2bf(v.w);
  reinterpret_cast<short4*>(out)[i] = o;
}

// ---------------- fp32 [R][C] -> bf16 [C][R] transpose-cast ----------------
__global__ __launch_bounds__(256) void transpose_cast_kernel(const float* __restrict__ in,
                                                             short* __restrict__ out,
                                                             int R, int C) {
  __shared__ float tile[32][33];
  int c0 = blockIdx.x * 32, r0 = blockIdx.y * 32;
  int tc = threadIdx.x & 31, tr = threadIdx.x >> 5;  // tr 0..7
#pragma unroll
  for (int p = 0; p < 4; ++p)
    tile[tr + p * 8][tc] = in[(size_t)(r0 + tr + p * 8) * C + c0 + tc];
  __syncthreads();
#pragma unroll
  for (int p = 0; p < 4; ++p)
    out[(size_t)(c0 + tr + p * 8) * R + r0 + tc] = f2bf(tile[tc][tr + p * 8]);
}

// ---------------- bf16 GEMM: C[M][ldc] = A[M][K] * Bt[N][K]^T + bias ----------------
// 128x128 tile, BK=32, 4 waves each 64x64 (4x4 frags of 16x16x32 MFMA).
// Staging via global_load_lds width=16 (m97 structure).
template <bool OBF, bool QSCALE>
__global__ __launch_bounds__(256) void gemm128_kernel(const short* __restrict__ A,
                                                      const short* __restrict__ Bt,
                                                      const float* __restrict__ bias,
                                                      void* __restrict__ Cout,
                                                      int K, int ldc) {
  __shared__ short Asm[128 * 32];
  __shared__ short Bsm[128 * 32];
  const int tid = threadIdx.x;
  const int lane = tid & 63, wid = tid >> 6;
  const int m0 = blockIdx.y * 128, n0 = blockIdx.x * 128;
  const int wm = wid >> 1, wn = wid & 1;
  const int lr = lane & 15, lg = lane >> 4;

  f32x4 acc[4][4] = {};

  const int s1 = tid, s2 = 256 + tid;
  const short* a1 = A + (size_t)(m0 + (s1 >> 2)) * K + (s1 & 3) * 8;
  const short* a2 = A + (size_t)(m0 + (s2 >> 2)) * K + (s2 & 3) * 8;
  const short* b1 = Bt + (size_t)(n0 + (s1 >> 2)) * K + (s1 & 3) * 8;
  const short* b2 = Bt + (size_t)(n0 + (s2 >> 2)) * K + (s2 & 3) * 8;

  for (int k0 = 0; k0 < K; k0 += 32) {
    __syncthreads();
    async_copy16(&Asm[s1 * 8], a1 + k0);
    async_copy16(&Asm[s2 * 8], a2 + k0);
    async_copy16(&Bsm[s1 * 8], b1 + k0);
    async_copy16(&Bsm[s2 * 8], b2 + k0);
    __syncthreads();

    bf16x8 af[4], bf[4];
#pragma unroll
    for (int mi = 0; mi < 4; ++mi)
      af[mi] = *(const bf16x8*)&Asm[(wm * 64 + mi * 16 + lr) * 32 + lg * 8];
#pragma unroll
    for (int ni = 0; ni < 4; ++ni)
      bf[ni] = *(const bf16x8*)&Bsm[(wn * 64 + ni * 16 + lr) * 32 + lg * 8];
    __builtin_amdgcn_s_setprio(1);
#pragma unroll
    for (int mi = 0; mi < 4; ++mi)
#pragma unroll
      for (int ni = 0; ni < 4; ++ni)
        acc[mi][ni] = __builtin_amdgcn_mfma_f32_16x16x32_bf16(af[mi], bf[ni], acc[mi][ni], 0, 0, 0);
    __builtin_amdgcn_s_setprio(0);
  }

#pragma unroll
  for (int ni = 0; ni < 4; ++ni) {
    const int col = n0 + wn * 64 + ni * 16 + lr;
    const float bv = bias[col];
    const float scale = (QSCALE && col < 1024) ? 0.18033688f : 1.0f;
#pragma unroll
    for (int mi = 0; mi < 4; ++mi) {
      const int row = m0 + wm * 64 + mi * 16 + lg * 4;
#pragma unroll
      for (int j = 0; j < 4; ++j) {
        const float v = (acc[mi][ni][j] + bv) * scale;
        if constexpr (OBF)
          ((short*)Cout)[(size_t)(row + j) * ldc + col] = f2bf(v);
        else
          ((float*)Cout)[(size_t)(row + j) * ldc + col] = v;
      }
    }
  }
}

// ---------------- V transpose: qkv V-part -> VT[b][h][64 d][2048 s] ----------------
__global__ __launch_bounds__(256) void vtrans_kernel(const short* __restrict__ qkv,
                                                     short* __restrict__ vt) {
  __shared__ short tile[64][72];
  const int tid = threadIdx.x;
  const int s0 = blockIdx.x * 64;
  const int h = blockIdx.y, b = blockIdx.z;
  const short* src = qkv + (size_t)(b * 2048 + s0) * 3072 + 2048 + h * 64;
#pragma unroll
  for (int p = 0; p < 2; ++p) {
    const int r = (tid >> 3) + p * 32;
    const int c0 = (tid & 7) * 8;
    *(s16x8*)&tile[r][c0] = *(const s16x8*)(src + (size_t)r * 3072 + c0);
  }
  __syncthreads();
  short* dst = vt + (size_t)(b * 16 + h) * 64 * 2048;
#pragma unroll
  for (int p = 0; p < 2; ++p) {
    const int d = (tid >> 3) + p * 32;
    const int sl0 = (tid & 7) * 8;
    s16x8 v;
#pragma unroll
    for (int i = 0; i < 8; ++i) v[i] = tile[sl0 + i][d];
    *(s16x8*)(dst + (size_t)d * 2048 + s0 + sl0) = v;
  }
}

// ---------------- causal flash attention ----------------
// 1D grid 1024 blocks, XCD-chunked swizzle. Block -> (pair px, h, b).
// pp loop: q-subtile {31-px, px} of 64 rows; 4 waves x 16 q-rows each.
// Every wave does exactly 33 kv-tiles total. Q pre-scaled by 0.125*log2e.
__global__ __launch_bounds__(256) void attn_kernel(const short* __restrict__ qkv,
                                                   const short* __restrict__ vt,
                                                   short* __restrict__ abuf) {
  __shared__ short P_lds[4][16][72];
  const int tid = threadIdx.x;
  const int lane = tid & 63, wid = tid >> 6;
  const int lr = lane & 15, lg = lane >> 4;

  // XCD-chunk swizzle (1024 % 8 == 0 -> bijective): XCD k gets contiguous work ids
  const int g = blockIdx.x;
  const int w = ((g & 7) << 7) | (g >> 3);
  const int px = w & 15, h = (w >> 4) & 15, b = w >> 8;

  const int ldq = 3072;
  const short* Qb = qkv + (size_t)b * 2048 * ldq + h * 64;
  const short* Kb = Qb + 1024;
  const short* Vtb = vt + (size_t)(b * 16 + h) * 64 * 2048;

  for (int pp = 0; pp < 2; ++pp) {
    const int qsub = pp ? px : 31 - px;
    const int qrowA = qsub * 64 + wid * 16;

    bf16x8 qf[2];
#pragma unroll
    for (int gg = 0; gg < 2; ++gg)
      qf[gg] = *(const bf16x8*)(Qb + (size_t)(qrowA + lr) * ldq + gg * 32 + lg * 8);

    f32x4 o[4] = {};
    float mst[4], lst[4];
#pragma unroll
    for (int j = 0; j < 4; ++j) { mst[j] = -__builtin_inff(); lst[j] = 0.f; }

    const int ntiles = qsub + 1;

    // prefetch K tile 0
    bf16x8 kf[4][2];
#pragma unroll
    for (int ni = 0; ni < 4; ++ni)
#pragma unroll
      for (int gg = 0; gg < 2; ++gg)
        kf[ni][gg] = *(const bf16x8*)(Kb + (size_t)(ni * 16 + lr) * ldq + gg * 32 + lg * 8);

    for (int t = 0; t < ntiles; ++t) {
      const int kvt = t << 6;

      f32x4 s[4];
      __builtin_amdgcn_s_setprio(1);
#pragma unroll
      for (int ni = 0; ni < 4; ++ni) {
        f32x4 z = {0.f, 0.f, 0.f, 0.f};
        s[ni] = z;
#pragma unroll
        for (int gg = 0; gg < 2; ++gg)
          s[ni] = __builtin_amdgcn_mfma_f32_16x16x32_bf16(qf[gg], kf[ni][gg], s[ni], 0, 0, 0);
      }
      __builtin_amdgcn_s_setprio(0);

      // prefetch next K tile (hidden under softmax + PV)
      bf16x8 kn[4][2];
      if (t + 1 < ntiles) {
        const int kvn = kvt + 64;
#pragma unroll
        for (int ni = 0; ni < 4; ++ni)
#pragma unroll
          for (int gg = 0; gg < 2; ++gg)
            kn[ni][gg] = *(const bf16x8*)(Kb + (size_t)(kvn + ni * 16 + lr) * ldq + gg * 32 + lg * 8);
      }
      // V for current tile: issue before softmax VALU so latency hides
      bf16x8 vb[4][2];
#pragma unroll
      for (int db = 0; db < 4; ++db)
#pragma unroll
        for (int gg = 0; gg < 2; ++gg)
          vb[db][gg] = *(const bf16x8*)(Vtb + (size_t)(db * 16 + lr) * 2048 + kvt + gg * 32 + lg * 8);

      // causal mask: only the diagonal tile needs it (t == qsub)
      if (kvt + 63 > qrowA) {
#pragma unroll
        for (int ni = 0; ni < 4; ++ni)
#pragma unroll
          for (int j = 0; j < 4; ++j) {
            const int q = qrowA + lg * 4 + j;
            const int kv = kvt + ni * 16 + lr;
            if (kv > q) s[ni][j] = -__builtin_inff();
          }
      }

      // per-row max (ni in-register, then 16-lane shfl tree)
      float v4[4];
#pragma unroll
      for (int j = 0; j < 4; ++j) {
        float v = fmaxf(fmaxf(s[0][j], s[1][j]), fmaxf(s[2][j], s[3][j]));
        v = fmaxf(v, __shfl_xor(v, 1, 64));
        v = fmaxf(v, __shfl_xor(v, 2, 64));
        v = fmaxf(v, __shfl_xor(v, 4, 64));
        v = fmaxf(v, __shfl_xor(v, 8, 64));
        v4[j] = v;
      }
      // defer-max (T13): skip rescale when growth <= 8 (exp2 domain, p <= 256)
      float gmax = fmaxf(fmaxf(v4[0] - mst[0], v4[1] - mst[1]),
                         fmaxf(v4[2] - mst[2], v4[3] - mst[3]));
      if (!__all(gmax <= 8.f)) {
#pragma unroll
        for (int j = 0; j < 4; ++j) {
          const float mn = fmaxf(mst[j], v4[j]);
          const float alpha = exp2f(mst[j] - mn);
          mst[j] = mn;
          lst[j] *= alpha;
#pragma unroll
          for (int db = 0; db < 4; ++db)
            o[db][j] *= alpha;
        }
      }

      float psum[4] = {};
#pragma unroll
      for (int ni = 0; ni < 4; ++ni)
#pragma unroll
        for (int j = 0; j < 4; ++j) {
          const float p = exp2f(s[ni][j] - mst[j]);
          psum[j] += p;
          P_lds[wid][lg * 4 + j][ni * 16 + lr] = f2bf(p);
        }
#pragma unroll
      for (int j = 0; j < 4; ++j) {
        float v = psum[j];
        v += __shfl_xor(v, 1, 64);
        v += __shfl_xor(v, 2, 64);
        v += __shfl_xor(v, 4, 64);
        v += __shfl_xor(v, 8, 64);
        lst[j] += v;
      }

      bf16x8 pa[2];
#pragma unroll
      for (int gg = 0; gg < 2; ++gg)
        pa[gg] = *(const bf16x8*)&P_lds[wid][lr][gg * 32 + lg * 8];

      __builtin_amdgcn_s_setprio(1);
#pragma unroll
      for (int db = 0; db < 4; ++db)
#pragma unroll
        for (int gg = 0; gg < 2; ++gg)
          o[db] = __builtin_amdgcn_mfma_f32_16x16x32_bf16(pa[gg], vb[db][gg], o[db], 0, 0, 0);
      __builtin_amdgcn_s_setprio(0);

#pragma unroll
      for (int ni = 0; ni < 4; ++ni)
#pragma unroll
        for (int gg = 0; gg < 2; ++gg)
          kf[ni][gg] = kn[ni][gg];
    }

    float rl[4];
#pragma unroll
    for (int j = 0; j < 4; ++j) rl[j] = 1.0f / lst[j];
#pragma unroll
    for (int db = 0; db < 4; ++db) {
      const int col = h * 64 + db * 16 + lr;
#pragma unroll
      for (int j = 0; j < 4; ++j) {
        const int row = b * 2048 + qrowA + lg * 4 + j;
        abuf[(size_t)row * 1024 + col] = f2bf(o[db][j] * rl[j]);
      }
    }
  }
}

extern "C" void kernel_launch(void* const* d_in, const int* in_sizes, int n_in,
                              void* d_out, int out_size, void* d_ws, size_t ws_size,
                              hipStream_t stream) {
  (void)in_sizes; (void)n_in; (void)out_size; (void)ws_size;
  const float* hs = (const float*)d_in[0];
  const float* w1 = (const float*)d_in[1];
  const float* b1 = (const float*)d_in[2];
  const float* w2 = (const float*)d_in[3];
  const float* b2 = (const float*)d_in[4];

  char* w = (char*)d_ws;
  short* Xb  = (short*)(w);                 // [8192][1024] bf16  16.78 MB
  short* W1T = (short*)(w + 16777216);      // [3072][1024] bf16   6.29 MB
  short* W2T = (short*)(w + 23068672);      // [1024][1024] bf16   2.10 MB
  short* QKV = (short*)(w + 25165824);      // [8192][3072] bf16  50.33 MB
  short* VT  = (short*)(w + 75497472);      // [64][64][2048] bf16 16.78 MB
  short* AB  = (short*)(w + 92274688);      // [8192][1024] bf16  16.78 MB

  cast_bf16_kernel<<<8192, 256, 0, stream>>>(hs, Xb);
  transpose_cast_kernel<<<dim3(96, 32), 256, 0, stream>>>(w1, W1T, 1024, 3072);
  transpose_cast_kernel<<<dim3(32, 32), 256, 0, stream>>>(w2, W2T, 1024, 1024);
  gemm128_kernel<true, true><<<dim3(24, 64), 256, 0, stream>>>(Xb, W1T, b1, QKV, 1024, 3072);
  vtrans_kernel<<<dim3(32, 16, 4), 256, 0, stream>>>(QKV, VT);
  attn_kernel<<<1024, 256, 0, stream>>>(QKV, VT, AB);
  gemm128_kernel<false, false><<<dim3(8, 64), 256, 0, stream>>>(AB, W2T, b2, d_out, 1024, 1024);
}

// Round 5
// 370.463 us; speedup vs baseline: 1.1812x; 1.1812x over previous
//
#include <hip/hip_runtime.h>
#include <stdint.h>

typedef __bf16 bf16x8 __attribute__((ext_vector_type(8)));
typedef short s16x8 __attribute__((ext_vector_type(8)));
typedef float f32x4 __attribute__((ext_vector_type(4)));

__device__ __forceinline__ short f2bf(float f) {
  union { __bf16 h; short s; } u;
  u.h = (__bf16)f;   // native v_cvt (RNE) — m240: don't hand-write
  return u.s;
}

// async global -> LDS direct copy, 16B per lane
__device__ __forceinline__ void async_copy16(short* lds, const short* g) {
  __builtin_amdgcn_global_load_lds((const __attribute__((address_space(1))) void*)g,
                                   (__attribute__((address_space(3))) void*)lds,
                                   16, 0, 0);
}

// ---------------- fp32 -> bf16 cast (4 elems/thread) ----------------
__global__ __launch_bounds__(256) void cast_bf16_kernel(const float* __restrict__ in,
                                                        short* __restrict__ out) {
  int i = blockIdx.x * 256 + threadIdx.x;
  float4 v = reinterpret_cast<const float4*>(in)[i];
  short4 o;
  o.x = f2bf(v.x); o.y = f2bf(v.y); o.z = f2bf(v.z); o.w = f2bf(v.w);
  reinterpret_cast<short4*>(out)[i] = o;
}

// ---------------- fp32 [R][C] -> bf16 [C][R] transpose-cast ----------------
__global__ __launch_bounds__(256) void transpose_cast_kernel(const float* __restrict__ in,
                                                             short* __restrict__ out,
                                                             int R, int C) {
  __shared__ float tile[32][33];
  int c0 = blockIdx.x * 32, r0 = blockIdx.y * 32;
  int tc = threadIdx.x & 31, tr = threadIdx.x >> 5;  // tr 0..7
#pragma unroll
  for (int p = 0; p < 4; ++p)
    tile[tr + p * 8][tc] = in[(size_t)(r0 + tr + p * 8) * C + c0 + tc];
  __syncthreads();
#pragma unroll
  for (int p = 0; p < 4; ++p)
    out[(size_t)(c0 + tr + p * 8) * R + r0 + tc] = f2bf(tile[tc][tr + p * 8]);
}

// ---------------- bf16 GEMM: C[M][ldc] = A[M][K] * Bt[N][K]^T + bias ----------------
// 128x128 tile, BK=32, 4 waves each 64x64 (4x4 frags of 16x16x32 MFMA).
// Staging via global_load_lds width=16 (m97 structure).
template <bool OBF, bool QSCALE>
__global__ __launch_bounds__(256) void gemm128_kernel(const short* __restrict__ A,
                                                      const short* __restrict__ Bt,
                                                      const float* __restrict__ bias,
                                                      void* __restrict__ Cout,
                                                      int K, int ldc) {
  __shared__ short Asm[128 * 32];
  __shared__ short Bsm[128 * 32];
  const int tid = threadIdx.x;
  const int lane = tid & 63, wid = tid >> 6;
  const int m0 = blockIdx.y * 128, n0 = blockIdx.x * 128;
  const int wm = wid >> 1, wn = wid & 1;
  const int lr = lane & 15, lg = lane >> 4;

  f32x4 acc[4][4] = {};

  const int s1 = tid, s2 = 256 + tid;
  const short* a1 = A + (size_t)(m0 + (s1 >> 2)) * K + (s1 & 3) * 8;
  const short* a2 = A + (size_t)(m0 + (s2 >> 2)) * K + (s2 & 3) * 8;
  const short* b1 = Bt + (size_t)(n0 + (s1 >> 2)) * K + (s1 & 3) * 8;
  const short* b2 = Bt + (size_t)(n0 + (s2 >> 2)) * K + (s2 & 3) * 8;

  for (int k0 = 0; k0 < K; k0 += 32) {
    __syncthreads();
    async_copy16(&Asm[s1 * 8], a1 + k0);
    async_copy16(&Asm[s2 * 8], a2 + k0);
    async_copy16(&Bsm[s1 * 8], b1 + k0);
    async_copy16(&Bsm[s2 * 8], b2 + k0);
    __syncthreads();

    bf16x8 af[4], bf[4];
#pragma unroll
    for (int mi = 0; mi < 4; ++mi)
      af[mi] = *(const bf16x8*)&Asm[(wm * 64 + mi * 16 + lr) * 32 + lg * 8];
#pragma unroll
    for (int ni = 0; ni < 4; ++ni)
      bf[ni] = *(const bf16x8*)&Bsm[(wn * 64 + ni * 16 + lr) * 32 + lg * 8];
    __builtin_amdgcn_s_setprio(1);
#pragma unroll
    for (int mi = 0; mi < 4; ++mi)
#pragma unroll
      for (int ni = 0; ni < 4; ++ni)
        acc[mi][ni] = __builtin_amdgcn_mfma_f32_16x16x32_bf16(af[mi], bf[ni], acc[mi][ni], 0, 0, 0);
    __builtin_amdgcn_s_setprio(0);
  }

#pragma unroll
  for (int ni = 0; ni < 4; ++ni) {
    const int col = n0 + wn * 64 + ni * 16 + lr;
    const float bv = bias[col];
    const float scale = (QSCALE && col < 1024) ? 0.18033688f : 1.0f;
#pragma unroll
    for (int mi = 0; mi < 4; ++mi) {
      const int row = m0 + wm * 64 + mi * 16 + lg * 4;
#pragma unroll
      for (int j = 0; j < 4; ++j) {
        const float v = (acc[mi][ni][j] + bv) * scale;
        if constexpr (OBF)
          ((short*)Cout)[(size_t)(row + j) * ldc + col] = f2bf(v);
        else
          ((float*)Cout)[(size_t)(row + j) * ldc + col] = v;
      }
    }
  }
}

// ---------------- V transpose: qkv V-part -> VT[b][h][64 d][2048 s] ----------------
__global__ __launch_bounds__(256) void vtrans_kernel(const short* __restrict__ qkv,
                                                     short* __restrict__ vt) {
  __shared__ short tile[64][72];
  const int tid = threadIdx.x;
  const int s0 = blockIdx.x * 64;
  const int h = blockIdx.y, b = blockIdx.z;
  const short* src = qkv + (size_t)(b * 2048 + s0) * 3072 + 2048 + h * 64;
#pragma unroll
  for (int p = 0; p < 2; ++p) {
    const int r = (tid >> 3) + p * 32;
    const int c0 = (tid & 7) * 8;
    *(s16x8*)&tile[r][c0] = *(const s16x8*)(src + (size_t)r * 3072 + c0);
  }
  __syncthreads();
  short* dst = vt + (size_t)(b * 16 + h) * 64 * 2048;
#pragma unroll
  for (int p = 0; p < 2; ++p) {
    const int d = (tid >> 3) + p * 32;
    const int sl0 = (tid & 7) * 8;
    s16x8 v;
#pragma unroll
    for (int i = 0; i < 8; ++i) v[i] = tile[sl0 + i][d];
    *(s16x8*)(dst + (size_t)d * 2048 + s0 + sl0) = v;
  }
}

// ---------------- causal flash attention ----------------
// 1D grid 512 blocks, XCD-chunked swizzle. Block -> (pair px, h, b).
// pp loop: q-tile {15-px, px} of 128 rows; 4 waves x 32 q-rows each (2 qb).
// Per-wave work uniform: ~34 kv-tiles. Q pre-scaled by 0.125*log2e.
__global__ __launch_bounds__(256) void attn_kernel(const short* __restrict__ qkv,
                                                   const short* __restrict__ vt,
                                                   short* __restrict__ abuf) {
  __shared__ short P_lds[4][32][72];
  const int tid = threadIdx.x;
  const int lane = tid & 63, wid = tid >> 6;
  const int lr = lane & 15, lg = lane >> 4;

  // XCD-chunk swizzle (512 % 8 == 0 -> bijective): XCD k gets 64 contiguous work ids
  const int g = blockIdx.x;
  const int w = ((g & 7) << 6) | (g >> 3);
  const int px = w & 7, h = (w >> 3) & 15, b = w >> 7;

  const int ldq = 3072;
  const short* Qb = qkv + (size_t)b * 2048 * ldq + h * 64;
  const short* Kb = Qb + 1024;
  const short* Vtb = vt + (size_t)(b * 16 + h) * 64 * 2048;

  for (int pp = 0; pp < 2; ++pp) {
    const int qtile = pp ? px : 15 - px;
    const int qrowA = qtile * 128 + wid * 32;

    bf16x8 qf[2][2];
#pragma unroll
    for (int qb = 0; qb < 2; ++qb)
#pragma unroll
      for (int gg = 0; gg < 2; ++gg)
        qf[qb][gg] = *(const bf16x8*)(Qb + (size_t)(qrowA + qb * 16 + lr) * ldq + gg * 32 + lg * 8);

    f32x4 o[2][4] = {};
    float mst[2][4], lst[2][4];
#pragma unroll
    for (int qb = 0; qb < 2; ++qb)
#pragma unroll
      for (int j = 0; j < 4; ++j) { mst[qb][j] = -__builtin_inff(); lst[qb][j] = 0.f; }

    const int ntiles = ((qrowA + 31) >> 6) + 1;

    // prefetch K tile 0
    bf16x8 kf[4][2];
#pragma unroll
    for (int ni = 0; ni < 4; ++ni)
#pragma unroll
      for (int gg = 0; gg < 2; ++gg)
        kf[ni][gg] = *(const bf16x8*)(Kb + (size_t)(ni * 16 + lr) * ldq + gg * 32 + lg * 8);

    for (int t = 0; t < ntiles; ++t) {
      const int kvt = t << 6;

      f32x4 s[2][4];
      __builtin_amdgcn_s_setprio(1);
#pragma unroll
      for (int qb = 0; qb < 2; ++qb)
#pragma unroll
        for (int ni = 0; ni < 4; ++ni) {
          f32x4 z = {0.f, 0.f, 0.f, 0.f};
          s[qb][ni] = z;
#pragma unroll
          for (int gg = 0; gg < 2; ++gg)
            s[qb][ni] = __builtin_amdgcn_mfma_f32_16x16x32_bf16(qf[qb][gg], kf[ni][gg], s[qb][ni], 0, 0, 0);
        }
      __builtin_amdgcn_s_setprio(0);

      // prefetch next K tile (hidden under softmax + PV)
      bf16x8 kn[4][2];
      if (t + 1 < ntiles) {
        const int kvn = kvt + 64;
#pragma unroll
        for (int ni = 0; ni < 4; ++ni)
#pragma unroll
          for (int gg = 0; gg < 2; ++gg)
            kn[ni][gg] = *(const bf16x8*)(Kb + (size_t)(kvn + ni * 16 + lr) * ldq + gg * 32 + lg * 8);
      }
      // V for current tile: issue before softmax VALU so latency hides
      bf16x8 vb[4][2];
#pragma unroll
      for (int db = 0; db < 4; ++db)
#pragma unroll
        for (int gg = 0; gg < 2; ++gg)
          vb[db][gg] = *(const bf16x8*)(Vtb + (size_t)(db * 16 + lr) * 2048 + kvt + gg * 32 + lg * 8);

      // causal mask only on diagonal-overlap tiles (wave-uniform branch)
      if (kvt + 63 > qrowA) {
#pragma unroll
        for (int qb = 0; qb < 2; ++qb)
#pragma unroll
          for (int ni = 0; ni < 4; ++ni)
#pragma unroll
            for (int j = 0; j < 4; ++j) {
              const int q = qrowA + qb * 16 + lg * 4 + j;
              const int kv = kvt + ni * 16 + lr;
              if (kv > q) s[qb][ni][j] = -__builtin_inff();
            }
      }

      // per-row max: ni-reduce in-register, then 16-lane shfl tree
      float v4[2][4];
#pragma unroll
      for (int qb = 0; qb < 2; ++qb)
#pragma unroll
        for (int j = 0; j < 4; ++j) {
          float v = fmaxf(fmaxf(s[qb][0][j], s[qb][1][j]), fmaxf(s[qb][2][j], s[qb][3][j]));
          v = fmaxf(v, __shfl_xor(v, 1, 64));
          v = fmaxf(v, __shfl_xor(v, 2, 64));
          v = fmaxf(v, __shfl_xor(v, 4, 64));
          v = fmaxf(v, __shfl_xor(v, 8, 64));
          v4[qb][j] = v;
        }
      // defer-max (T13): skip o-rescale when max growth <= 8 (exp2 domain, p <= 256)
      float gmax = -__builtin_inff();
#pragma unroll
      for (int qb = 0; qb < 2; ++qb)
#pragma unroll
        for (int j = 0; j < 4; ++j) gmax = fmaxf(gmax, v4[qb][j] - mst[qb][j]);
      if (!__all(gmax <= 8.f)) {
#pragma unroll
        for (int qb = 0; qb < 2; ++qb)
#pragma unroll
          for (int j = 0; j < 4; ++j) {
            const float mn = fmaxf(mst[qb][j], v4[qb][j]);
            const float alpha = exp2f(mst[qb][j] - mn);
            mst[qb][j] = mn;
            lst[qb][j] *= alpha;
#pragma unroll
            for (int db = 0; db < 4; ++db)
              o[qb][db][j] *= alpha;
          }
      }

      float psum[2][4] = {};
#pragma unroll
      for (int qb = 0; qb < 2; ++qb)
#pragma unroll
        for (int ni = 0; ni < 4; ++ni)
#pragma unroll
          for (int j = 0; j < 4; ++j) {
            const float p = exp2f(s[qb][ni][j] - mst[qb][j]);
            psum[qb][j] += p;
            P_lds[wid][qb * 16 + lg * 4 + j][ni * 16 + lr] = f2bf(p);
          }
#pragma unroll
      for (int qb = 0; qb < 2; ++qb)
#pragma unroll
        for (int j = 0; j < 4; ++j) {
          float v = psum[qb][j];
          v += __shfl_xor(v, 1, 64);
          v += __shfl_xor(v, 2, 64);
          v += __shfl_xor(v, 4, 64);
          v += __shfl_xor(v, 8, 64);
          lst[qb][j] += v;
        }

      bf16x8 pa[2][2];
#pragma unroll
      for (int qb = 0; qb < 2; ++qb)
#pragma unroll
        for (int gg = 0; gg < 2; ++gg)
          pa[qb][gg] = *(const bf16x8*)&P_lds[wid][qb * 16 + lr][gg * 32 + lg * 8];

      __builtin_amdgcn_s_setprio(1);
#pragma unroll
      for (int qb = 0; qb < 2; ++qb)
#pragma unroll
        for (int db = 0; db < 4; ++db)
#pragma unroll
          for (int gg = 0; gg < 2; ++gg)
            o[qb][db] = __builtin_amdgcn_mfma_f32_16x16x32_bf16(pa[qb][gg], vb[db][gg], o[qb][db], 0, 0, 0);
      __builtin_amdgcn_s_setprio(0);

#pragma unroll
      for (int ni = 0; ni < 4; ++ni)
#pragma unroll
        for (int gg = 0; gg < 2; ++gg)
          kf[ni][gg] = kn[ni][gg];
    }

#pragma unroll
    for (int qb = 0; qb < 2; ++qb) {
      float rl[4];
#pragma unroll
      for (int j = 0; j < 4; ++j) rl[j] = 1.0f / lst[qb][j];
#pragma unroll
      for (int db = 0; db < 4; ++db) {
        const int col = h * 64 + db * 16 + lr;
#pragma unroll
        for (int j = 0; j < 4; ++j) {
          const int row = b * 2048 + qrowA + qb * 16 + lg * 4 + j;
          abuf[(size_t)row * 1024 + col] = f2bf(o[qb][db][j] * rl[j]);
        }
      }
    }
  }
}

extern "C" void kernel_launch(void* const* d_in, const int* in_sizes, int n_in,
                              void* d_out, int out_size, void* d_ws, size_t ws_size,
                              hipStream_t stream) {
  (void)in_sizes; (void)n_in; (void)out_size; (void)ws_size;
  const float* hs = (const float*)d_in[0];
  const float* w1 = (const float*)d_in[1];
  const float* b1 = (const float*)d_in[2];
  const float* w2 = (const float*)d_in[3];
  const float* b2 = (const float*)d_in[4];

  char* w = (char*)d_ws;
  short* Xb  = (short*)(w);                 // [8192][1024] bf16  16.78 MB
  short* W1T = (short*)(w + 16777216);      // [3072][1024] bf16   6.29 MB
  short* W2T = (short*)(w + 23068672);      // [1024][1024] bf16   2.10 MB
  short* QKV = (short*)(w + 25165824);      // [8192][3072] bf16  50.33 MB
  short* VT  = (short*)(w + 75497472);      // [64][64][2048] bf16 16.78 MB
  short* AB  = (short*)(w + 92274688);      // [8192][1024] bf16  16.78 MB

  cast_bf16_kernel<<<8192, 256, 0, stream>>>(hs, Xb);
  transpose_cast_kernel<<<dim3(96, 32), 256, 0, stream>>>(w1, W1T, 1024, 3072);
  transpose_cast_kernel<<<dim3(32, 32), 256, 0, stream>>>(w2, W2T, 1024, 1024);
  gemm128_kernel<true, true><<<dim3(24, 64), 256, 0, stream>>>(Xb, W1T, b1, QKV, 1024, 3072);
  vtrans_kernel<<<dim3(32, 16, 4), 256, 0, stream>>>(QKV, VT);
  attn_kernel<<<512, 256, 0, stream>>>(QKV, VT, AB);
  gemm128_kernel<false, false><<<dim3(8, 64), 256, 0, stream>>>(AB, W2T, b2, d_out, 1024, 1024);
}

// Round 7
// 359.105 us; speedup vs baseline: 1.2186x; 1.0316x over previous
//
#include <hip/hip_runtime.h>
#include <stdint.h>

typedef __bf16 bf16x8 __attribute__((ext_vector_type(8)));
typedef short s16x8 __attribute__((ext_vector_type(8)));
typedef float f32x4 __attribute__((ext_vector_type(4)));

__device__ __forceinline__ short f2bf(float f) {
  union { __bf16 h; short s; } u;
  u.h = (__bf16)f;   // native v_cvt (RNE) — m240: don't hand-write
  return u.s;
}

// async global -> LDS direct copy, 16B per lane
__device__ __forceinline__ void async_copy16(short* lds, const short* g) {
  __builtin_amdgcn_global_load_lds((const __attribute__((address_space(1))) void*)g,
                                   (__attribute__((address_space(3))) void*)lds,
                                   16, 0, 0);
}

// ---------------- fp32 -> bf16 cast (4 elems/thread) ----------------
__global__ __launch_bounds__(256) void cast_bf16_kernel(const float* __restrict__ in,
                                                        short* __restrict__ out) {
  int i = blockIdx.x * 256 + threadIdx.x;
  float4 v = reinterpret_cast<const float4*>(in)[i];
  short4 o;
  o.x = f2bf(v.x); o.y = f2bf(v.y); o.z = f2bf(v.z); o.w = f2bf(v.w);
  reinterpret_cast<short4*>(out)[i] = o;
}

// ---------------- fp32 [R][C] -> bf16 [C][R] transpose-cast ----------------
__global__ __launch_bounds__(256) void transpose_cast_kernel(const float* __restrict__ in,
                                                             short* __restrict__ out,
                                                             int R, int C) {
  __shared__ float tile[32][33];
  int c0 = blockIdx.x * 32, r0 = blockIdx.y * 32;
  int tc = threadIdx.x & 31, tr = threadIdx.x >> 5;  // tr 0..7
#pragma unroll
  for (int p = 0; p < 4; ++p)
    tile[tr + p * 8][tc] = in[(size_t)(r0 + tr + p * 8) * C + c0 + tc];
  __syncthreads();
#pragma unroll
  for (int p = 0; p < 4; ++p)
    out[(size_t)(c0 + tr + p * 8) * R + r0 + tc] = f2bf(tile[tc][tr + p * 8]);
}

// ---------------- bf16 GEMM: C[M][ldc] = A[M][K] * Bt[N][K]^T + bias ----------------
// 128x128 tile, BK=32, 4 waves each 64x64 (4x4 frags of 16x16x32 MFMA).
// Staging via global_load_lds width=16 (m97 structure).
template <bool OBF, bool QSCALE>
__global__ __launch_bounds__(256) void gemm128_kernel(const short* __restrict__ A,
                                                      const short* __restrict__ Bt,
                                                      const float* __restrict__ bias,
                                                      void* __restrict__ Cout,
                                                      int K, int ldc) {
  __shared__ short Asm[128 * 32];
  __shared__ short Bsm[128 * 32];
  const int tid = threadIdx.x;
  const int lane = tid & 63, wid = tid >> 6;
  const int m0 = blockIdx.y * 128, n0 = blockIdx.x * 128;
  const int wm = wid >> 1, wn = wid & 1;
  const int lr = lane & 15, lg = lane >> 4;

  f32x4 acc[4][4] = {};

  const int s1 = tid, s2 = 256 + tid;
  const short* a1 = A + (size_t)(m0 + (s1 >> 2)) * K + (s1 & 3) * 8;
  const short* a2 = A + (size_t)(m0 + (s2 >> 2)) * K + (s2 & 3) * 8;
  const short* b1 = Bt + (size_t)(n0 + (s1 >> 2)) * K + (s1 & 3) * 8;
  const short* b2 = Bt + (size_t)(n0 + (s2 >> 2)) * K + (s2 & 3) * 8;

  for (int k0 = 0; k0 < K; k0 += 32) {
    __syncthreads();
    async_copy16(&Asm[s1 * 8], a1 + k0);
    async_copy16(&Asm[s2 * 8], a2 + k0);
    async_copy16(&Bsm[s1 * 8], b1 + k0);
    async_copy16(&Bsm[s2 * 8], b2 + k0);
    __syncthreads();

    bf16x8 af[4], bf[4];
#pragma unroll
    for (int mi = 0; mi < 4; ++mi)
      af[mi] = *(const bf16x8*)&Asm[(wm * 64 + mi * 16 + lr) * 32 + lg * 8];
#pragma unroll
    for (int ni = 0; ni < 4; ++ni)
      bf[ni] = *(const bf16x8*)&Bsm[(wn * 64 + ni * 16 + lr) * 32 + lg * 8];
    __builtin_amdgcn_s_setprio(1);
#pragma unroll
    for (int mi = 0; mi < 4; ++mi)
#pragma unroll
      for (int ni = 0; ni < 4; ++ni)
        acc[mi][ni] = __builtin_amdgcn_mfma_f32_16x16x32_bf16(af[mi], bf[ni], acc[mi][ni], 0, 0, 0);
    __builtin_amdgcn_s_setprio(0);
  }

#pragma unroll
  for (int ni = 0; ni < 4; ++ni) {
    const int col = n0 + wn * 64 + ni * 16 + lr;
    const float bv = bias[col];
    const float scale = (QSCALE && col < 1024) ? 0.18033688f : 1.0f;
#pragma unroll
    for (int mi = 0; mi < 4; ++mi) {
      const int row = m0 + wm * 64 + mi * 16 + lg * 4;
#pragma unroll
      for (int j = 0; j < 4; ++j) {
        const float v = (acc[mi][ni][j] + bv) * scale;
        if constexpr (OBF)
          ((short*)Cout)[(size_t)(row + j) * ldc + col] = f2bf(v);
        else
          ((float*)Cout)[(size_t)(row + j) * ldc + col] = v;
      }
    }
  }
}

// ---------------- V transpose: qkv V-part -> VT[b][h][64 d][2048 s] ----------------
__global__ __launch_bounds__(256) void vtrans_kernel(const short* __restrict__ qkv,
                                                     short* __restrict__ vt) {
  __shared__ short tile[64][72];
  const int tid = threadIdx.x;
  const int s0 = blockIdx.x * 64;
  const int h = blockIdx.y, b = blockIdx.z;
  const short* src = qkv + (size_t)(b * 2048 + s0) * 3072 + 2048 + h * 64;
#pragma unroll
  for (int p = 0; p < 2; ++p) {
    const int r = (tid >> 3) + p * 32;
    const int c0 = (tid & 7) * 8;
    *(s16x8*)&tile[r][c0] = *(const s16x8*)(src + (size_t)r * 3072 + c0);
  }
  __syncthreads();
  short* dst = vt + (size_t)(b * 16 + h) * 64 * 2048;
#pragma unroll
  for (int p = 0; p < 2; ++p) {
    const int d = (tid >> 3) + p * 32;
    const int sl0 = (tid & 7) * 8;
    s16x8 v;
#pragma unroll
    for (int i = 0; i < 8; ++i) v[i] = tile[sl0 + i][d];
    *(s16x8*)(dst + (size_t)d * 2048 + s0 + sl0) = v;
  }
}

// ---------------- causal flash attention ----------------
// grid 256 blocks (1/CU), XCD-chunked swizzle. Block -> (pair px, h, b).
// 256-row q-tiles; pair {7-px, px}. 4 waves x 64 q-rows (4 qb of 16).
// pp=1 reverses wave order -> every wave does exactly 33 kv-tile units.
// Per-qb pipeline caps register liveness; l-sum reduced once at end.
// Q pre-scaled by 0.125*log2e (exp2 domain).
__global__ __launch_bounds__(256) void attn_kernel(const short* __restrict__ qkv,
                                                   const short* __restrict__ vt,
                                                   short* __restrict__ abuf) {
  __shared__ short P_lds[4][64][72];
  const int tid = threadIdx.x;
  const int lane = tid & 63, wid = tid >> 6;
  const int lr = lane & 15, lg = lane >> 4;

  // XCD-chunk swizzle (256 % 8 == 0 -> bijective): XCD k gets 32 contiguous ids
  const int g = blockIdx.x;
  const int w = ((g & 7) << 5) | (g >> 3);
  const int px = w & 3, h = (w >> 2) & 15, b = w >> 6;

  const int ldq = 3072;
  const short* Qb = qkv + (size_t)b * 2048 * ldq + h * 64;
  const short* Kb = Qb + 1024;
  const short* Vtb = vt + (size_t)(b * 16 + h) * 64 * 2048;

  for (int pp = 0; pp < 2; ++pp) {
    const int qtile = pp ? px : 7 - px;
    const int wrow = pp ? (3 - wid) : wid;     // balance waves across the pair
    const int qrowW = qtile * 256 + wrow * 64; // wave's 64 q-rows

    bf16x8 qf[4][2];
#pragma unroll
    for (int qb = 0; qb < 4; ++qb)
#pragma unroll
      for (int gg = 0; gg < 2; ++gg)
        qf[qb][gg] = *(const bf16x8*)(Qb + (size_t)(qrowW + qb * 16 + lr) * ldq + gg * 32 + lg * 8);

    f32x4 o[4][4] = {};
    float mst[4][4], lsum[4][4];
#pragma unroll
    for (int qb = 0; qb < 4; ++qb)
#pragma unroll
      for (int j = 0; j < 4; ++j) { mst[qb][j] = -__builtin_inff(); lsum[qb][j] = 0.f; }

    const int ntiles = (qrowW >> 6) + 1;

    // K tile 0
    bf16x8 kf[4][2];
#pragma unroll
    for (int ni = 0; ni < 4; ++ni)
#pragma unroll
      for (int gg = 0; gg < 2; ++gg)
        kf[ni][gg] = *(const bf16x8*)(Kb + (size_t)(ni * 16 + lr) * ldq + gg * 32 + lg * 8);

    for (int t = 0; t < ntiles; ++t) {
      const int kvt = t << 6;
      const bool diag = (t == ntiles - 1);

      // V loads early: complete under QK + softmax
      bf16x8 vb[4][2];
#pragma unroll
      for (int db = 0; db < 4; ++db)
#pragma unroll
        for (int gg = 0; gg < 2; ++gg)
          vb[db][gg] = *(const bf16x8*)(Vtb + (size_t)(db * 16 + lr) * 2048 + kvt + gg * 32 + lg * 8);

      // per-qb pipeline: QK(qb) -> softmax(qb); s[qb] dies before next phase
#pragma unroll
      for (int qb = 0; qb < 4; ++qb) {
        f32x4 s[4];
        __builtin_amdgcn_s_setprio(1);
#pragma unroll
        for (int ni = 0; ni < 4; ++ni) {
          f32x4 z = {0.f, 0.f, 0.f, 0.f};
          s[ni] = z;
#pragma unroll
          for (int gg = 0; gg < 2; ++gg)
            s[ni] = __builtin_amdgcn_mfma_f32_16x16x32_bf16(qf[qb][gg], kf[ni][gg], s[ni], 0, 0, 0);
        }
        __builtin_amdgcn_s_setprio(0);

        if (diag) {
#pragma unroll
          for (int ni = 0; ni < 4; ++ni)
#pragma unroll
            for (int j = 0; j < 4; ++j) {
              const int q = qrowW + qb * 16 + lg * 4 + j;
              const int kv = kvt + ni * 16 + lr;
              if (kv > q) s[ni][j] = -__builtin_inff();
            }
        }

        // per-row max: ni in-register, then 16-lane shfl tree
        float v4[4];
#pragma unroll
        for (int j = 0; j < 4; ++j) {
          float v = fmaxf(fmaxf(s[0][j], s[1][j]), fmaxf(s[2][j], s[3][j]));
          v = fmaxf(v, __shfl_xor(v, 1, 64));
          v = fmaxf(v, __shfl_xor(v, 2, 64));
          v = fmaxf(v, __shfl_xor(v, 4, 64));
          v = fmaxf(v, __shfl_xor(v, 8, 64));
          v4[j] = v;
        }
        // defer-max (T13), per-qb gate: skip o-rescale when growth <= 8
        const float gmax = fmaxf(fmaxf(v4[0] - mst[qb][0], v4[1] - mst[qb][1]),
                                 fmaxf(v4[2] - mst[qb][2], v4[3] - mst[qb][3]));
        if (!__all(gmax <= 8.f)) {
#pragma unroll
          for (int j = 0; j < 4; ++j) {
            const float mn = fmaxf(mst[qb][j], v4[j]);
            const float alpha = exp2f(mst[qb][j] - mn);
            mst[qb][j] = mn;
            lsum[qb][j] *= alpha;
#pragma unroll
            for (int db = 0; db < 4; ++db)
              o[qb][db][j] *= alpha;
          }
        }

        // p = exp2(s-m); accumulate per-lane partial l; stage P for PV
#pragma unroll
        for (int ni = 0; ni < 4; ++ni)
#pragma unroll
          for (int j = 0; j < 4; ++j) {
            const float p = exp2f(s[ni][j] - mst[qb][j]);
            lsum[qb][j] += p;
            P_lds[wid][qb * 16 + lg * 4 + j][ni * 16 + lr] = f2bf(p);
          }
      }

      // prefetch next K tile (in flight across PV)
      if (t + 1 < ntiles) {
        const int kvn = kvt + 64;
#pragma unroll
        for (int ni = 0; ni < 4; ++ni)
#pragma unroll
          for (int gg = 0; gg < 2; ++gg)
            kf[ni][gg] = *(const bf16x8*)(Kb + (size_t)(kvn + ni * 16 + lr) * ldq + gg * 32 + lg * 8);
      }

      // PV
      bf16x8 pa[4][2];
#pragma unroll
      for (int qb = 0; qb < 4; ++qb)
#pragma unroll
        for (int gg = 0; gg < 2; ++gg)
          pa[qb][gg] = *(const bf16x8*)&P_lds[wid][qb * 16 + lr][gg * 32 + lg * 8];

      __builtin_amdgcn_s_setprio(1);
#pragma unroll
      for (int qb = 0; qb < 4; ++qb)
#pragma unroll
        for (int db = 0; db < 4; ++db)
#pragma unroll
          for (int gg = 0; gg < 2; ++gg)
            o[qb][db] = __builtin_amdgcn_mfma_f32_16x16x32_bf16(pa[qb][gg], vb[db][gg], o[qb][db], 0, 0, 0);
      __builtin_amdgcn_s_setprio(0);
    }

    // deferred l reduction (linear; per-lane partials share row-uniform scale)
#pragma unroll
    for (int qb = 0; qb < 4; ++qb) {
      float rl[4];
#pragma unroll
      for (int j = 0; j < 4; ++j) {
        float v = lsum[qb][j];
        v += __shfl_xor(v, 1, 64);
        v += __shfl_xor(v, 2, 64);
        v += __shfl_xor(v, 4, 64);
        v += __shfl_xor(v, 8, 64);
        rl[j] = 1.0f / v;
      }
#pragma unroll
      for (int db = 0; db < 4; ++db) {
        const int col = h * 64 + db * 16 + lr;
#pragma unroll
        for (int j = 0; j < 4; ++j) {
          const int row = b * 2048 + qrowW + qb * 16 + lg * 4 + j;
          abuf[(size_t)row * 1024 + col] = f2bf(o[qb][db][j] * rl[j]);
        }
      }
    }
  }
}

extern "C" void kernel_launch(void* const* d_in, const int* in_sizes, int n_in,
                              void* d_out, int out_size, void* d_ws, size_t ws_size,
                              hipStream_t stream) {
  (void)in_sizes; (void)n_in; (void)out_size; (void)ws_size;
  const float* hs = (const float*)d_in[0];
  const float* w1 = (const float*)d_in[1];
  const float* b1 = (const float*)d_in[2];
  const float* w2 = (const float*)d_in[3];
  const float* b2 = (const float*)d_in[4];

  char* w = (char*)d_ws;
  short* Xb  = (short*)(w);                 // [8192][1024] bf16  16.78 MB
  short* W1T = (short*)(w + 16777216);      // [3072][1024] bf16   6.29 MB
  short* W2T = (short*)(w + 23068672);      // [1024][1024] bf16   2.10 MB
  short* QKV = (short*)(w + 25165824);      // [8192][3072] bf16  50.33 MB
  short* VT  = (short*)(w + 75497472);      // [64][64][2048] bf16 16.78 MB
  short* AB  = (short*)(w + 92274688);      // [8192][1024] bf16  16.78 MB

  cast_bf16_kernel<<<8192, 256, 0, stream>>>(hs, Xb);
  transpose_cast_kernel<<<dim3(96, 32), 256, 0, stream>>>(w1, W1T, 1024, 3072);
  transpose_cast_kernel<<<dim3(32, 32), 256, 0, stream>>>(w2, W2T, 1024, 1024);
  gemm128_kernel<true, true><<<dim3(24, 64), 256, 0, stream>>>(Xb, W1T, b1, QKV, 1024, 3072);
  vtrans_kernel<<<dim3(32, 16, 4), 256, 0, stream>>>(QKV, VT);
  attn_kernel<<<256, 256, 0, stream>>>(QKV, VT, AB);
  gemm128_kernel<false, false><<<dim3(8, 64), 256, 0, stream>>>(AB, W2T, b2, d_out, 1024, 1024);
}